// Round 6
// baseline (432.254 us; speedup 1.0000x reference)
//
#include <hip/hip_runtime.h>
#include <hip/hip_fp16.h>

#define NN 1024
#define BATCH 8
#define CDIM 16
#define NITER 50
#define NDENSE 7           // dense warmup iterations (last one also builds candidates)
#define CAP 160            // max candidates per row

// eps = 0.05^2 = 0.0025
// K_SCALE = 1/(eps*ln2); EPS_LN2 = eps*ln2 = 1/K_SCALE; log2(1/1024) = -10.
static constexpr float K_SCALE = 577.0780163555854f;
static constexpr float EPS_LN2 = 0.0017328679513998632f;
// candidate margin: 0.6 natural cost units, expressed in t-units (x K_SCALE)
static constexpr float MARGIN_T = 0.6f * 577.0780163555854f;

#if __has_builtin(__builtin_amdgcn_exp2f)
#define EXP2F(x) __builtin_amdgcn_exp2f(x)
#else
#define EXP2F(x) exp2f(x)
#endif
#if __has_builtin(__builtin_amdgcn_logf)
#define LOG2F(x) __builtin_amdgcn_logf(x)
#else
#define LOG2F(x) log2f(x)
#endif

// 4 cost matrices in fp16: 0 = C_xy, 1 = C_yx, 2 = C_xx, 3 = C_yy   (64 MiB)
__device__ __half g_C16[4][BATCH][NN][NN];
// double-buffered potentials: [parity][which: 0=f,1=g,2=p,3=q][batch][row]
__device__ float g_pot[2][4][BATCH][NN];
__device__ float g_mse_acc;
// sparse candidate lists: packed (j << 16) | fp16-bits(C_ij)
__device__ __align__(16) unsigned int g_cand[4][BATCH][NN][CAP];   // ~21 MiB
__device__ unsigned int g_cnt[4][BATCH][NN];

__global__ __launch_bounds__(256) void init_kernel() {
    int idx = blockIdx.x * 256 + threadIdx.x;
    float* p = &g_pot[0][0][0][0];
    if (idx < 4 * BATCH * NN) p[idx] = 0.0f;
    if (idx == 0) g_mse_acc = 0.0f;
}

__global__ __launch_bounds__(256) void mse_kernel(const float* __restrict__ a,
                                                  const float* __restrict__ b) {
    int tid = threadIdx.x;
    int idx = blockIdx.x * 256 + tid;
    const int total = BATCH * NN * CDIM;  // 131072
    float acc = 0.0f;
    for (int i = idx; i < total; i += gridDim.x * 256) {
        float d = a[i] - b[i];
        acc = fmaf(d, d, acc);
    }
    #pragma unroll
    for (int off = 32; off; off >>= 1) acc += __shfl_xor(acc, off, 64);
    __shared__ float red[4];
    int lane = tid & 63, wid = tid >> 6;
    if (lane == 0) red[wid] = acc;
    __syncthreads();
    if (tid == 0) {
        atomicAdd(&g_mse_acc, red[0] + red[1] + red[2] + red[3]);
    }
}

struct alignas(8) H4 { __half2 a, b; };

// Gram-form cost. Block = (matrix, batch, 16-row group). The 16 x-rows are
// staged in LDS once; thread owns 4 y-rows in registers, reused across rows.
__global__ __launch_bounds__(256) void cost_kernel(const float* __restrict__ x,
                                                   const float* __restrict__ y) {
    int bid = blockIdx.x;
    int m = bid >> 9;            // 0..3
    int b = (bid >> 6) & 7;
    int ig = bid & 63;           // 16-row group
    const float* X = (m == 1 || m == 3) ? y : x;
    const float* Y = (m == 0 || m == 3) ? y : x;
    int tid = threadIdx.x;
    int j0 = tid * 4;

    __shared__ float xs[16 * CDIM];
    __shared__ float x2s[16];
    xs[tid] = X[(size_t)(b * NN + ig * 16) * CDIM + tid];
    __syncthreads();
    if (tid < 16) {
        float a = 0.0f;
        #pragma unroll
        for (int k = 0; k < CDIM; ++k) a = fmaf(xs[tid * CDIM + k], xs[tid * CDIM + k], a);
        x2s[tid] = 0.5f * a;
    }

    float yr[4][16];
    const float4* Y4 = reinterpret_cast<const float4*>(Y + (size_t)(b * NN + j0) * CDIM);
    #pragma unroll
    for (int rr = 0; rr < 4; ++rr) {
        #pragma unroll
        for (int q = 0; q < 4; ++q) {
            float4 v = Y4[rr * 4 + q];
            yr[rr][q * 4 + 0] = v.x; yr[rr][q * 4 + 1] = v.y;
            yr[rr][q * 4 + 2] = v.z; yr[rr][q * 4 + 3] = v.w;
        }
    }
    float y2h[4];
    #pragma unroll
    for (int rr = 0; rr < 4; ++rr) {
        float acc = 0.0f;
        #pragma unroll
        for (int k = 0; k < CDIM; ++k) acc = fmaf(yr[rr][k], yr[rr][k], acc);
        y2h[rr] = 0.5f * acc;
    }
    __syncthreads();

    #pragma unroll 1
    for (int r = 0; r < 16; ++r) {
        float xv[CDIM];
        #pragma unroll
        for (int k = 0; k < CDIM; ++k) xv[k] = xs[r * CDIM + k];   // LDS broadcast
        float x2h = x2s[r];

        float acc[4];
        #pragma unroll
        for (int rr = 0; rr < 4; ++rr) {
            float a = x2h + y2h[rr];
            #pragma unroll
            for (int k = 0; k < CDIM; ++k) a = fmaf(xv[k], -yr[rr][k], a);
            acc[rr] = a;
        }
        H4 out;
        out.a = __floats2half2_rn(acc[0], acc[1]);
        out.b = __floats2half2_rn(acc[2], acc[3]);
        int i = ig * 16 + r;
        *reinterpret_cast<H4*>(&g_C16[m][b][i][j0]) = out;
    }
}

__device__ inline float2 cvt2(unsigned int u) {
    __half2 h;
    *reinterpret_cast<unsigned int*>(&h) = u;
    return __half22float2(h);
}

// Dense wave-per-row softmin iteration. Optionally (BUILD) also emits the
// per-row candidate set {j : t_j >= rowmax - MARGIN_T} for the sparse phase.
template <bool BUILD>
__global__ __launch_bounds__(256) void iter_kernel_t(int parity) {
    int bid = blockIdx.x;
    int p = bid >> 9;            // pass / matrix
    int b = (bid >> 6) & 7;
    int rg = bid & 63;
    int hsel = (p == 0) ? 1 : (p == 1) ? 0 : p;

    int tid = threadIdx.x;
    int lane = tid & 63, wid = tid >> 6;

    const float* __restrict__ hin  = g_pot[parity][hsel][b];
    const float* __restrict__ oldp = g_pot[parity][p][b];
    float* __restrict__ outp       = g_pot[parity ^ 1][p][b];

    float hs[16];
    {
        const float4* h4 = reinterpret_cast<const float4*>(hin);
        float4 a0 = h4[lane * 2], a1 = h4[lane * 2 + 1];
        float4 b0 = h4[128 + lane * 2], b1 = h4[128 + lane * 2 + 1];
        hs[0] = a0.x * K_SCALE;  hs[1] = a0.y * K_SCALE;
        hs[2] = a0.z * K_SCALE;  hs[3] = a0.w * K_SCALE;
        hs[4] = a1.x * K_SCALE;  hs[5] = a1.y * K_SCALE;
        hs[6] = a1.z * K_SCALE;  hs[7] = a1.w * K_SCALE;
        hs[8]  = b0.x * K_SCALE; hs[9]  = b0.y * K_SCALE;
        hs[10] = b0.z * K_SCALE; hs[11] = b0.w * K_SCALE;
        hs[12] = b1.x * K_SCALE; hs[13] = b1.y * K_SCALE;
        hs[14] = b1.z * K_SCALE; hs[15] = b1.w * K_SCALE;
    }

    #pragma unroll
    for (int r = 0; r < 4; ++r) {
        int i = rg * 16 + wid * 4 + r;
        const uint4* crow = reinterpret_cast<const uint4*>(&g_C16[p][b][i][0]);
        uint4 ca = crow[lane];
        uint4 cb = crow[64 + lane];

        float t[16];
        {
            float2 f;
            f = cvt2(ca.x); t[0] = fmaf(f.x, -K_SCALE, hs[0]);  t[1] = fmaf(f.y, -K_SCALE, hs[1]);
            f = cvt2(ca.y); t[2] = fmaf(f.x, -K_SCALE, hs[2]);  t[3] = fmaf(f.y, -K_SCALE, hs[3]);
            f = cvt2(ca.z); t[4] = fmaf(f.x, -K_SCALE, hs[4]);  t[5] = fmaf(f.y, -K_SCALE, hs[5]);
            f = cvt2(ca.w); t[6] = fmaf(f.x, -K_SCALE, hs[6]);  t[7] = fmaf(f.y, -K_SCALE, hs[7]);
            f = cvt2(cb.x); t[8] = fmaf(f.x, -K_SCALE, hs[8]);  t[9] = fmaf(f.y, -K_SCALE, hs[9]);
            f = cvt2(cb.y); t[10] = fmaf(f.x, -K_SCALE, hs[10]); t[11] = fmaf(f.y, -K_SCALE, hs[11]);
            f = cvt2(cb.z); t[12] = fmaf(f.x, -K_SCALE, hs[12]); t[13] = fmaf(f.y, -K_SCALE, hs[13]);
            f = cvt2(cb.w); t[14] = fmaf(f.x, -K_SCALE, hs[14]); t[15] = fmaf(f.y, -K_SCALE, hs[15]);
        }

        float mx = t[0];
        #pragma unroll
        for (int k = 1; k < 16; ++k) mx = fmaxf(mx, t[k]);
        #pragma unroll
        for (int off = 32; off; off >>= 1) mx = fmaxf(mx, __shfl_xor(mx, off, 64));

        float s = 0.0f;
        #pragma unroll
        for (int k = 0; k < 16; ++k) s += EXP2F(t[k] - mx);
        #pragma unroll
        for (int off = 32; off; off >>= 1) s += __shfl_xor(s, off, 64);

        if (lane == 0) {
            float res = -EPS_LN2 * (mx - 10.0f + LOG2F(s));
            outp[i] = 0.5f * (oldp[i] + res);
        }

        if (BUILD) {
            float thr = mx - MARGIN_T;
            int c = 0;
            #pragma unroll
            for (int k = 0; k < 16; ++k) c += (t[k] >= thr) ? 1 : 0;
            int incl = c;
            #pragma unroll
            for (int off = 1; off < 64; off <<= 1) {
                int v = __shfl_up(incl, off, 64);
                if (lane >= off) incl += v;
            }
            int excl = incl - c;
            int total = __shfl(incl, 63, 64);
            if (lane == 0) g_cnt[p][b][i] = (unsigned)(total < CAP ? total : CAP);

            union U4 { uint4 q; unsigned w[4]; } A, B2;
            A.q = ca; B2.q = cb;
            int slot = excl;
            #pragma unroll
            for (int k = 0; k < 16; ++k) {
                if (t[k] >= thr) {
                    if (slot < CAP) {
                        unsigned hb = (k < 8) ? A.w[k >> 1] : B2.w[(k - 8) >> 1];
                        hb = (hb >> ((k & 1) * 16)) & 0xffffu;
                        unsigned j = (k < 8) ? (unsigned)(lane * 8 + k)
                                             : (unsigned)(512 + lane * 8 + (k - 8));
                        g_cand[p][b][i][slot] = (j << 16) | hb;
                    }
                    ++slot;
                }
            }
        }
    }
}

// Persistent sparse phase: ALL remaining iterations in one launch.
// Dependency structure factors per batch: {f<->g} coupled, {p} self, {q} self.
// Grid = 8 batches x 3 roles = 24 blocks of 1024 threads; each block keeps its
// potentials (scaled by K_SCALE) in LDS, double-buffered, __syncthreads between
// iterations. res_scaled = -(mx - 10 + log2 s) exactly (EPS_LN2 = 1/K_SCALE).
__global__ __launch_bounds__(1024) void persist_kernel(int start_par, int niter) {
    int bid = blockIdx.x;
    int role = bid % 3;          // 0 = f&g, 1 = p, 2 = q
    int b = bid / 3;
    int tid = threadIdx.x;
    int c = tid & 3;
    int row = tid >> 2;          // 0..255

    __shared__ float sh[2][2][NN];   // [parity][side][row], side: 0=f/p/q, 1=g

    if (role == 0) {
        for (int k = tid; k < NN; k += 1024) {
            sh[0][0][k] = g_pot[start_par][0][b][k] * K_SCALE;
            sh[0][1][k] = g_pot[start_par][1][b][k] * K_SCALE;
        }
    } else {
        int which = (role == 1) ? 2 : 3;
        for (int k = tid; k < NN; k += 1024) {
            sh[0][0][k] = g_pot[start_par][which][b][k] * K_SCALE;
        }
    }
    __syncthreads();

    int nrows = (role == 0) ? 2048 : 1024;
    int pass_self = (role == 1) ? 2 : 3;

    for (int it = 0; it < niter; ++it) {
        int cur = it & 1, nxt = cur ^ 1;
        for (int r0 = row; r0 < nrows; r0 += 256) {
            int pass, i, hside, oside;
            if (role == 0) {
                if (r0 < 1024) { pass = 0; i = r0;        hside = 1; oside = 0; }
                else           { pass = 1; i = r0 - 1024; hside = 0; oside = 1; }
            } else { pass = pass_self; i = r0; hside = 0; oside = 0; }

            const float* __restrict__ h2 = sh[cur][hside];
            int cnt = (int)g_cnt[pass][b][i];
            const uint4* __restrict__ cd4 =
                reinterpret_cast<const uint4*>(&g_cand[pass][b][i][0]);

            float m = -3.0e38f;
            float s = 0.0f;
            int nstep = (cnt + 15) >> 4;
            for (int k = 0; k < nstep; ++k) {
                int base = k * 16 + c * 4;
                uint4 u = cd4[k * 4 + c];
                unsigned w0 = u.x, w1 = u.y, w2 = u.z, w3 = u.w;
                __half h0, h1, h3, h4v;
                *reinterpret_cast<unsigned short*>(&h0)  = (unsigned short)(w0 & 0xffffu);
                *reinterpret_cast<unsigned short*>(&h1)  = (unsigned short)(w1 & 0xffffu);
                *reinterpret_cast<unsigned short*>(&h3)  = (unsigned short)(w2 & 0xffffu);
                *reinterpret_cast<unsigned short*>(&h4v) = (unsigned short)(w3 & 0xffffu);
                float t0 = fmaf(__half2float(h0),  -K_SCALE, h2[(w0 >> 16) & 1023]);
                float t1 = fmaf(__half2float(h1),  -K_SCALE, h2[(w1 >> 16) & 1023]);
                float t2 = fmaf(__half2float(h3),  -K_SCALE, h2[(w2 >> 16) & 1023]);
                float t3 = fmaf(__half2float(h4v), -K_SCALE, h2[(w3 >> 16) & 1023]);
                t0 = (base + 0 < cnt) ? t0 : -3.0e38f;
                t1 = (base + 1 < cnt) ? t1 : -3.0e38f;
                t2 = (base + 2 < cnt) ? t2 : -3.0e38f;
                t3 = (base + 3 < cnt) ? t3 : -3.0e38f;
                float sm = fmaxf(fmaxf(t0, t1), fmaxf(t2, t3));
                float nm = fmaxf(m, sm);
                s = s * EXP2F(m - nm) + EXP2F(t0 - nm) + EXP2F(t1 - nm)
                                      + EXP2F(t2 - nm) + EXP2F(t3 - nm);
                m = nm;
            }
            #pragma unroll
            for (int off = 1; off <= 2; off <<= 1) {
                float m2 = __shfl_xor(m, off, 64);
                float s2 = __shfl_xor(s, off, 64);
                float nm = fmaxf(m, m2);
                s = s * EXP2F(m - nm) + s2 * EXP2F(m2 - nm);
                m = nm;
            }
            if (c == 0) {
                float res_s = -(m - 10.0f + LOG2F(s));    // scaled by K_SCALE
                sh[nxt][oside][i] = 0.5f * (sh[cur][oside][i] + res_s);
            }
        }
        __syncthreads();
    }

    int fin = niter & 1;
    if (role == 0) {
        for (int k = tid; k < NN; k += 1024) {
            g_pot[0][0][b][k] = sh[fin][0][k] * EPS_LN2;
            g_pot[0][1][b][k] = sh[fin][1][k] * EPS_LN2;
        }
    } else {
        int which = (role == 1) ? 2 : 3;
        for (int k = tid; k < NN; k += 1024) {
            g_pot[0][which][b][k] = sh[fin][0][k] * EPS_LN2;
        }
    }
}

__global__ __launch_bounds__(256) void epilogue_kernel(float* __restrict__ out) {
    int tid = threadIdx.x;
    const float* f = &g_pot[0][0][0][0];
    const float* g = &g_pot[0][1][0][0];
    const float* pp = &g_pot[0][2][0][0];
    const float* q = &g_pot[0][3][0][0];
    float acc = 0.0f;
    for (int idx = tid; idx < BATCH * NN; idx += 256) {
        acc += (f[idx] - pp[idx]) + (g[idx] - q[idx]);
    }
    #pragma unroll
    for (int off = 32; off; off >>= 1) acc += __shfl_xor(acc, off, 64);
    __shared__ float red[4];
    int lane = tid & 63, wid = tid >> 6;
    if (lane == 0) red[wid] = acc;
    __syncthreads();
    if (tid == 0) {
        float ot = (red[0] + red[1] + red[2] + red[3]) / (float)(BATCH * NN);
        float mse = g_mse_acc / (float)(BATCH * NN * CDIM);
        out[0] = mse + ot;
        out[1] = mse;
        out[2] = ot;
    }
}

extern "C" void kernel_launch(void* const* d_in, const int* in_sizes, int n_in,
                              void* d_out, int out_size, void* d_ws, size_t ws_size,
                              hipStream_t stream) {
    const float* pred = (const float*)d_in[0];
    const float* gt   = (const float*)d_in[1];
    float* out = (float*)d_out;

    init_kernel<<<(4 * BATCH * NN + 255) / 256, 256, 0, stream>>>();
    mse_kernel<<<64, 256, 0, stream>>>(pred, gt);
    cost_kernel<<<4 * BATCH * 64, 256, 0, stream>>>(pred, gt);
    // dense warmup: iterations 0 .. NDENSE-1; the last one also builds candidates
    for (int t = 0; t < NDENSE - 1; ++t) {
        iter_kernel_t<false><<<4 * BATCH * 64, 256, 0, stream>>>(t & 1);
    }
    iter_kernel_t<true><<<4 * BATCH * 64, 256, 0, stream>>>((NDENSE - 1) & 1);
    // persistent sparse phase: iterations NDENSE .. NITER-1 in ONE launch
    persist_kernel<<<BATCH * 3, 1024, 0, stream>>>(NDENSE & 1, NITER - NDENSE);
    epilogue_kernel<<<1, 256, 0, stream>>>(out);
}

// Round 8
// 253.567 us; speedup vs baseline: 1.7047x; 1.7047x over previous
//
#include <hip/hip_runtime.h>
#include <hip/hip_fp16.h>

#define NN 1024
#define BATCH 8
#define CDIM 16
#define NITER 50           // MUST be 50: trajectory not converged (round-7 lesson)
#define NDENSE_FULL 3      // full-row dense iters t=0,1,2 (t=2 builds coarse list)
#define T_FINE_BUILD 6     // fine list built during iter 6 (same anchor as round 5)
#define CAPC 512           // coarse candidates per row (margin 4.0)
#define CAPF 160           // fine candidates per row (margin 0.6)

// eps = 0.05^2 = 0.0025
// K_SCALE = 1/(eps*ln2); EPS_LN2 = eps*ln2; log2(1/1024) = -10 exactly.
static constexpr float K_SCALE = 577.0780163555854f;
static constexpr float EPS_LN2 = 0.0017328679513998632f;
static constexpr float MARGIN_T = 0.6f * 577.0780163555854f;   // fine margin (t-units)
static constexpr float MARGIN_C = 4.0f * 577.0780163555854f;   // coarse margin (t-units)

#if __has_builtin(__builtin_amdgcn_exp2f)
#define EXP2F(x) __builtin_amdgcn_exp2f(x)
#else
#define EXP2F(x) exp2f(x)
#endif
#if __has_builtin(__builtin_amdgcn_logf)
#define LOG2F(x) __builtin_amdgcn_logf(x)
#else
#define LOG2F(x) log2f(x)
#endif

// 4 cost matrices in fp16: 0 = C_xy, 1 = C_yx, 2 = C_xx, 3 = C_yy   (64 MiB)
__device__ __half g_C16[4][BATCH][NN][NN];
// double-buffered potentials: [parity][which: 0=f,1=g,2=p,3=q][batch][row]
__device__ float g_pot[2][4][BATCH][NN];
__device__ float g_mse_part[128];
// candidate lists: packed (j << 16) | fp16-bits(C_ij), flat [pass][batch][row][cap]
__device__ __align__(16) unsigned g_cand_c[4 * BATCH * NN * CAPC];  // ~67 MiB
__device__ unsigned g_cnt_c[4 * BATCH * NN];
__device__ __align__(16) unsigned g_cand_f[4 * BATCH * NN * CAPF];  // ~21 MiB
__device__ unsigned g_cnt_f[4 * BATCH * NN];

// Zero potentials + per-block MSE partials (no atomics -> deterministic).
__global__ __launch_bounds__(256) void init_mse_kernel(const float* __restrict__ a,
                                                       const float* __restrict__ b) {
    int tid = threadIdx.x;
    int idx = blockIdx.x * 256 + tid;
    float* p = &g_pot[0][0][0][0];
    if (idx < 4 * BATCH * NN) p[idx] = 0.0f;

    const int total = BATCH * NN * CDIM;  // 131072
    float acc = 0.0f;
    for (int i = idx; i < total; i += gridDim.x * 256) {
        float d = a[i] - b[i];
        acc = fmaf(d, d, acc);
    }
    #pragma unroll
    for (int off = 32; off; off >>= 1) acc += __shfl_xor(acc, off, 64);
    __shared__ float red[4];
    int lane = tid & 63, wid = tid >> 6;
    if (lane == 0) red[wid] = acc;
    __syncthreads();
    if (tid == 0) g_mse_part[blockIdx.x] = red[0] + red[1] + red[2] + red[3];
}

struct alignas(8) H4 { __half2 a, b; };

// Gram-form cost. Block = (matrix, batch, 16-row group).
__global__ __launch_bounds__(256) void cost_kernel(const float* __restrict__ x,
                                                   const float* __restrict__ y) {
    int bid = blockIdx.x;
    int m = bid >> 9;
    int b = (bid >> 6) & 7;
    int ig = bid & 63;
    const float* X = (m == 1 || m == 3) ? y : x;
    const float* Y = (m == 0 || m == 3) ? y : x;
    int tid = threadIdx.x;
    int j0 = tid * 4;

    __shared__ float xs[16 * CDIM];
    __shared__ float x2s[16];
    xs[tid] = X[(size_t)(b * NN + ig * 16) * CDIM + tid];
    __syncthreads();
    if (tid < 16) {
        float a = 0.0f;
        #pragma unroll
        for (int k = 0; k < CDIM; ++k) a = fmaf(xs[tid * CDIM + k], xs[tid * CDIM + k], a);
        x2s[tid] = 0.5f * a;
    }

    float yr[4][16];
    const float4* Y4 = reinterpret_cast<const float4*>(Y + (size_t)(b * NN + j0) * CDIM);
    #pragma unroll
    for (int rr = 0; rr < 4; ++rr) {
        #pragma unroll
        for (int q = 0; q < 4; ++q) {
            float4 v = Y4[rr * 4 + q];
            yr[rr][q * 4 + 0] = v.x; yr[rr][q * 4 + 1] = v.y;
            yr[rr][q * 4 + 2] = v.z; yr[rr][q * 4 + 3] = v.w;
        }
    }
    float y2h[4];
    #pragma unroll
    for (int rr = 0; rr < 4; ++rr) {
        float acc = 0.0f;
        #pragma unroll
        for (int k = 0; k < CDIM; ++k) acc = fmaf(yr[rr][k], yr[rr][k], acc);
        y2h[rr] = 0.5f * acc;
    }
    __syncthreads();

    #pragma unroll 1
    for (int r = 0; r < 16; ++r) {
        float xv[CDIM];
        #pragma unroll
        for (int k = 0; k < CDIM; ++k) xv[k] = xs[r * CDIM + k];
        float x2h = x2s[r];

        float acc[4];
        #pragma unroll
        for (int rr = 0; rr < 4; ++rr) {
            float a = x2h + y2h[rr];
            #pragma unroll
            for (int k = 0; k < CDIM; ++k) a = fmaf(xv[k], -yr[rr][k], a);
            acc[rr] = a;
        }
        H4 out;
        out.a = __floats2half2_rn(acc[0], acc[1]);
        out.b = __floats2half2_rn(acc[2], acc[3]);
        int i = ig * 16 + r;
        *reinterpret_cast<H4*>(&g_C16[m][b][i][j0]) = out;
    }
}

__device__ inline float2 cvt2(unsigned int u) {
    __half2 h;
    *reinterpret_cast<unsigned int*>(&h) = u;
    return __half22float2(h);
}

// Dense wave-per-row softmin iteration. BUILD emits the COARSE candidate set
// {j : t_j >= rowmax - MARGIN_C} for the pruned phase.
template <bool BUILD>
__global__ __launch_bounds__(256) void iter_kernel_t(int parity) {
    int bid = blockIdx.x;
    int p = bid >> 9;
    int b = (bid >> 6) & 7;
    int rg = bid & 63;
    int hsel = (p == 0) ? 1 : (p == 1) ? 0 : p;

    int tid = threadIdx.x;
    int lane = tid & 63, wid = tid >> 6;

    const float* __restrict__ hin  = g_pot[parity][hsel][b];
    const float* __restrict__ oldp = g_pot[parity][p][b];
    float* __restrict__ outp       = g_pot[parity ^ 1][p][b];

    float hs[16];
    {
        const float4* h4 = reinterpret_cast<const float4*>(hin);
        float4 a0 = h4[lane * 2], a1 = h4[lane * 2 + 1];
        float4 b0 = h4[128 + lane * 2], b1 = h4[128 + lane * 2 + 1];
        hs[0] = a0.x * K_SCALE;  hs[1] = a0.y * K_SCALE;
        hs[2] = a0.z * K_SCALE;  hs[3] = a0.w * K_SCALE;
        hs[4] = a1.x * K_SCALE;  hs[5] = a1.y * K_SCALE;
        hs[6] = a1.z * K_SCALE;  hs[7] = a1.w * K_SCALE;
        hs[8]  = b0.x * K_SCALE; hs[9]  = b0.y * K_SCALE;
        hs[10] = b0.z * K_SCALE; hs[11] = b0.w * K_SCALE;
        hs[12] = b1.x * K_SCALE; hs[13] = b1.y * K_SCALE;
        hs[14] = b1.z * K_SCALE; hs[15] = b1.w * K_SCALE;
    }

    #pragma unroll
    for (int r = 0; r < 4; ++r) {
        int i = rg * 16 + wid * 4 + r;
        const uint4* crow = reinterpret_cast<const uint4*>(&g_C16[p][b][i][0]);
        uint4 ca = crow[lane];
        uint4 cb = crow[64 + lane];

        float t[16];
        {
            float2 f;
            f = cvt2(ca.x); t[0] = fmaf(f.x, -K_SCALE, hs[0]);  t[1] = fmaf(f.y, -K_SCALE, hs[1]);
            f = cvt2(ca.y); t[2] = fmaf(f.x, -K_SCALE, hs[2]);  t[3] = fmaf(f.y, -K_SCALE, hs[3]);
            f = cvt2(ca.z); t[4] = fmaf(f.x, -K_SCALE, hs[4]);  t[5] = fmaf(f.y, -K_SCALE, hs[5]);
            f = cvt2(ca.w); t[6] = fmaf(f.x, -K_SCALE, hs[6]);  t[7] = fmaf(f.y, -K_SCALE, hs[7]);
            f = cvt2(cb.x); t[8] = fmaf(f.x, -K_SCALE, hs[8]);  t[9] = fmaf(f.y, -K_SCALE, hs[9]);
            f = cvt2(cb.y); t[10] = fmaf(f.x, -K_SCALE, hs[10]); t[11] = fmaf(f.y, -K_SCALE, hs[11]);
            f = cvt2(cb.z); t[12] = fmaf(f.x, -K_SCALE, hs[12]); t[13] = fmaf(f.y, -K_SCALE, hs[13]);
            f = cvt2(cb.w); t[14] = fmaf(f.x, -K_SCALE, hs[14]); t[15] = fmaf(f.y, -K_SCALE, hs[15]);
        }

        float mx = t[0];
        #pragma unroll
        for (int k = 1; k < 16; ++k) mx = fmaxf(mx, t[k]);
        #pragma unroll
        for (int off = 32; off; off >>= 1) mx = fmaxf(mx, __shfl_xor(mx, off, 64));

        float s = 0.0f;
        #pragma unroll
        for (int k = 0; k < 16; ++k) s += EXP2F(t[k] - mx);
        #pragma unroll
        for (int off = 32; off; off >>= 1) s += __shfl_xor(s, off, 64);

        if (lane == 0) {
            float res = -EPS_LN2 * (mx - 10.0f + LOG2F(s));
            outp[i] = 0.5f * (oldp[i] + res);
        }

        if (BUILD) {
            size_t rowid = (size_t)((p * BATCH + b) * NN + i);
            float thr = mx - MARGIN_C;
            int c = 0;
            #pragma unroll
            for (int k = 0; k < 16; ++k) c += (t[k] >= thr) ? 1 : 0;
            int incl = c;
            #pragma unroll
            for (int off = 1; off < 64; off <<= 1) {
                int v = __shfl_up(incl, off, 64);
                if (lane >= off) incl += v;
            }
            int excl = incl - c;
            int total = __shfl(incl, 63, 64);
            if (lane == 0) g_cnt_c[rowid] = (unsigned)(total < CAPC ? total : CAPC);

            union U4 { uint4 q; unsigned w[4]; } A, B2;
            A.q = ca; B2.q = cb;
            unsigned* dst = &g_cand_c[rowid * CAPC];
            int slot = excl;
            #pragma unroll
            for (int k = 0; k < 16; ++k) {
                if (t[k] >= thr) {
                    if (slot < CAPC) {
                        unsigned hb = (k < 8) ? A.w[k >> 1] : B2.w[(k - 8) >> 1];
                        hb = (hb >> ((k & 1) * 16)) & 0xffffu;
                        unsigned j = (k < 8) ? (unsigned)(lane * 8 + k)
                                             : (unsigned)(512 + lane * 8 + (k - 8));
                        dst[slot] = (j << 16) | hb;
                    }
                    ++slot;
                }
            }
        }
    }
}

// Sparse iteration over a candidate list (coarse or fine). 4 lanes per row,
// uint4 loads, one-pass online logsumexp, 2-step shfl merge.
// BUILDF: additionally extract the fine list {t >= rowmax - MARGIN_T}.
// Grid: 4 passes x 8 batches x 16 row-groups (64 rows each) = 512 blocks.
template <bool BUILDF, bool COARSE_SRC>
__global__ __launch_bounds__(256) void sparse_iter_t(int parity) {
    int bid = blockIdx.x;
    int p = bid >> 7;
    int b = (bid >> 4) & 7;
    int rg = bid & 15;
    int hsel = (p == 0) ? 1 : (p == 1) ? 0 : p;

    const float* __restrict__ hin  = g_pot[parity][hsel][b];
    const float* __restrict__ oldp = g_pot[parity][p][b];
    float* __restrict__ outp       = g_pot[parity ^ 1][p][b];

    __shared__ float h2[NN];
    {
        const float4* h4 = reinterpret_cast<const float4*>(hin);
        float4 v = h4[threadIdx.x];
        v.x *= K_SCALE; v.y *= K_SCALE; v.z *= K_SCALE; v.w *= K_SCALE;
        reinterpret_cast<float4*>(h2)[threadIdx.x] = v;
    }
    __syncthreads();

    int tid = threadIdx.x;
    int lane = tid & 63, wid = tid >> 6;
    int c = lane & 3;
    int i = rg * 64 + wid * 16 + (lane >> 2);
    size_t rowid = (size_t)((p * BATCH + b) * NN + i);

    const unsigned* __restrict__ candsrc = COARSE_SRC ? g_cand_c : g_cand_f;
    const int cap = COARSE_SRC ? CAPC : CAPF;
    int cnt = (int)(COARSE_SRC ? g_cnt_c[rowid] : g_cnt_f[rowid]);
    const uint4* __restrict__ cd4 =
        reinterpret_cast<const uint4*>(candsrc + rowid * cap);

    float m = -3.0e38f;
    float s = 0.0f;
    int nstep = (cnt + 15) >> 4;
    for (int k = 0; k < nstep; ++k) {
        int base = k * 16 + c * 4;
        uint4 u = cd4[k * 4 + c];
        float2 fa, fb;
        __half hh;
        *reinterpret_cast<unsigned short*>(&hh) = (unsigned short)(u.x & 0xffffu);
        float t0 = fmaf(__half2float(hh), -K_SCALE, h2[(u.x >> 16) & 1023]);
        *reinterpret_cast<unsigned short*>(&hh) = (unsigned short)(u.y & 0xffffu);
        float t1 = fmaf(__half2float(hh), -K_SCALE, h2[(u.y >> 16) & 1023]);
        *reinterpret_cast<unsigned short*>(&hh) = (unsigned short)(u.z & 0xffffu);
        float t2 = fmaf(__half2float(hh), -K_SCALE, h2[(u.z >> 16) & 1023]);
        *reinterpret_cast<unsigned short*>(&hh) = (unsigned short)(u.w & 0xffffu);
        float t3 = fmaf(__half2float(hh), -K_SCALE, h2[(u.w >> 16) & 1023]);
        t0 = (base + 0 < cnt) ? t0 : -3.0e38f;
        t1 = (base + 1 < cnt) ? t1 : -3.0e38f;
        t2 = (base + 2 < cnt) ? t2 : -3.0e38f;
        t3 = (base + 3 < cnt) ? t3 : -3.0e38f;
        float sm = fmaxf(fmaxf(t0, t1), fmaxf(t2, t3));
        float nm = fmaxf(m, sm);
        s = s * EXP2F(m - nm) + EXP2F(t0 - nm) + EXP2F(t1 - nm)
                              + EXP2F(t2 - nm) + EXP2F(t3 - nm);
        m = nm;
    }
    #pragma unroll
    for (int off = 1; off <= 2; off <<= 1) {
        float m2 = __shfl_xor(m, off, 64);
        float s2 = __shfl_xor(s, off, 64);
        float nm = fmaxf(m, m2);
        s = s * EXP2F(m - nm) + s2 * EXP2F(m2 - nm);
        m = nm;
    }
    if (c == 0) {
        float res = -EPS_LN2 * (m - 10.0f + LOG2F(s));
        outp[i] = 0.5f * (oldp[i] + res);
    }

    if (BUILDF) {
        // Extract fine list from the coarse list using pre-update h (exact
        // same anchor as the round-5 fine build). m = true row max.
        float thr = m - MARGIN_T;
        int cl = 0;
        for (int k = 0; k < nstep; ++k) {
            int base = k * 16 + c * 4;
            uint4 u = cd4[k * 4 + c];
            unsigned w[4] = {u.x, u.y, u.z, u.w};
            #pragma unroll
            for (int o = 0; o < 4; ++o) {
                if (base + o < cnt) {
                    __half hh;
                    *reinterpret_cast<unsigned short*>(&hh) = (unsigned short)(w[o] & 0xffffu);
                    float tv = fmaf(__half2float(hh), -K_SCALE, h2[(w[o] >> 16) & 1023]);
                    if (tv >= thr) ++cl;
                }
            }
        }
        int g0 = lane & ~3;
        int c0 = __shfl(cl, g0 + 0, 64);
        int c1 = __shfl(cl, g0 + 1, 64);
        int c2 = __shfl(cl, g0 + 2, 64);
        int c3 = __shfl(cl, g0 + 3, 64);
        int excl = ((c >= 1) ? c0 : 0) + ((c >= 2) ? c1 : 0) + ((c >= 3) ? c2 : 0);
        int total = c0 + c1 + c2 + c3;
        if (c == 0) g_cnt_f[rowid] = (unsigned)(total < CAPF ? total : CAPF);
        unsigned* dst = &g_cand_f[rowid * CAPF];
        int slot = excl;
        for (int k = 0; k < nstep; ++k) {
            int base = k * 16 + c * 4;
            uint4 u = cd4[k * 4 + c];
            unsigned w[4] = {u.x, u.y, u.z, u.w};
            #pragma unroll
            for (int o = 0; o < 4; ++o) {
                if (base + o < cnt) {
                    __half hh;
                    *reinterpret_cast<unsigned short*>(&hh) = (unsigned short)(w[o] & 0xffffu);
                    float tv = fmaf(__half2float(hh), -K_SCALE, h2[(w[o] >> 16) & 1023]);
                    if (tv >= thr) {
                        if (slot < CAPF) dst[slot] = w[o];
                        ++slot;
                    }
                }
            }
        }
    }
}

__global__ __launch_bounds__(256) void epilogue_kernel(float* __restrict__ out) {
    int tid = threadIdx.x;
    const float* f = &g_pot[0][0][0][0];
    const float* g = &g_pot[0][1][0][0];
    const float* pp = &g_pot[0][2][0][0];
    const float* q = &g_pot[0][3][0][0];
    float acc = 0.0f;
    for (int idx = tid; idx < BATCH * NN; idx += 256) {
        acc += (f[idx] - pp[idx]) + (g[idx] - q[idx]);
    }
    float macc = (tid < 128) ? g_mse_part[tid] : 0.0f;
    #pragma unroll
    for (int off = 32; off; off >>= 1) {
        acc += __shfl_xor(acc, off, 64);
        macc += __shfl_xor(macc, off, 64);
    }
    __shared__ float red[4], redm[4];
    int lane = tid & 63, wid = tid >> 6;
    if (lane == 0) { red[wid] = acc; redm[wid] = macc; }
    __syncthreads();
    if (tid == 0) {
        float ot = (red[0] + red[1] + red[2] + red[3]) / (float)(BATCH * NN);
        float mse = (redm[0] + redm[1] + redm[2] + redm[3]) / (float)(BATCH * NN * CDIM);
        out[0] = mse + ot;
        out[1] = mse;
        out[2] = ot;
    }
}

extern "C" void kernel_launch(void* const* d_in, const int* in_sizes, int n_in,
                              void* d_out, int out_size, void* d_ws, size_t ws_size,
                              hipStream_t stream) {
    const float* pred = (const float*)d_in[0];
    const float* gt   = (const float*)d_in[1];
    float* out = (float*)d_out;

    init_mse_kernel<<<128, 256, 0, stream>>>(pred, gt);
    cost_kernel<<<4 * BATCH * 64, 256, 0, stream>>>(pred, gt);
    // full dense iters t=0,1; t=2 also builds the coarse list (margin 4.0)
    iter_kernel_t<false><<<4 * BATCH * 64, 256, 0, stream>>>(0);   // t=0
    iter_kernel_t<false><<<4 * BATCH * 64, 256, 0, stream>>>(1);   // t=1
    iter_kernel_t<true ><<<4 * BATCH * 64, 256, 0, stream>>>(0);   // t=2 + coarse build
    // coarse-pruned iters t=3..5
    sparse_iter_t<false, true><<<4 * BATCH * 16, 256, 0, stream>>>(1);  // t=3
    sparse_iter_t<false, true><<<4 * BATCH * 16, 256, 0, stream>>>(0);  // t=4
    sparse_iter_t<false, true><<<4 * BATCH * 16, 256, 0, stream>>>(1);  // t=5
    // t=6: coarse-pruned iter + fine build (margin 0.6, anchor = pre-update h)
    sparse_iter_t<true, true><<<4 * BATCH * 16, 256, 0, stream>>>(0);   // t=6
    // fine sparse phase t=7..49
    for (int t = T_FINE_BUILD + 1; t < NITER; ++t) {
        sparse_iter_t<false, false><<<4 * BATCH * 16, 256, 0, stream>>>(t & 1);
    }
    // NITER even -> final potentials in g_pot[0]
    epilogue_kernel<<<1, 256, 0, stream>>>(out);
}